// Round 15
// baseline (168.818 us; speedup 1.0000x reference)
//
#include <hip/hip_runtime.h>

#define NN 4096
#define NE 131072
#define DIN 256
#define DHID 512
#define DOUT 64
#define DCAT 1536
#define NBINS 65536
#define HALF_E 65536

typedef __attribute__((ext_vector_type(8))) short short8;
typedef __attribute__((ext_vector_type(4))) float f32x4;

__device__ inline unsigned short bf16rne(float f){
  unsigned u = __float_as_uint(f);
  unsigned r = u + 0x7FFFu + ((u>>16)&1u);
  return (unsigned short)(r>>16);
}
__device__ inline float bf2f(unsigned short u){ return __uint_as_float(((unsigned)u)<<16); }

// ---------------- Threefry-2x32 (JAX-compatible) ----------------
struct K2 { unsigned a, b; };
__host__ __device__ constexpr unsigned rotl32(unsigned x, unsigned d){ return (x<<d)|(x>>(32u-d)); }
__host__ __device__ constexpr K2 tf2x32(unsigned k0, unsigned k1, unsigned x0, unsigned x1){
  unsigned k2 = k0 ^ k1 ^ 0x1BD11BDAu;
  x0 += k0; x1 += k1;
  x0+=x1; x1=rotl32(x1,13); x1^=x0;
  x0+=x1; x1=rotl32(x1,15); x1^=x0;
  x0+=x1; x1=rotl32(x1,26); x1^=x0;
  x0+=x1; x1=rotl32(x1, 6); x1^=x0;
  x0+=k1; x1+=k2+1u;
  x0+=x1; x1=rotl32(x1,17); x1^=x0;
  x0+=x1; x1=rotl32(x1,29); x1^=x0;
  x0+=x1; x1=rotl32(x1,16); x1^=x0;
  x0+=x1; x1=rotl32(x1,24); x1^=x0;
  x0+=k2; x1+=k0+2u;
  x0+=x1; x1=rotl32(x1,13); x1^=x0;
  x0+=x1; x1=rotl32(x1,15); x1^=x0;
  x0+=x1; x1=rotl32(x1,26); x1^=x0;
  x0+=x1; x1=rotl32(x1, 6); x1^=x0;
  x0+=k0; x1+=k1+3u;
  x0+=x1; x1=rotl32(x1,17); x1^=x0;
  x0+=x1; x1=rotl32(x1,29); x1^=x0;
  x0+=x1; x1=rotl32(x1,16); x1^=x0;
  x0+=x1; x1=rotl32(x1,24); x1^=x0;
  x0+=k1; x1+=k2+4u;
  x0+=x1; x1=rotl32(x1,13); x1^=x0;
  x0+=x1; x1=rotl32(x1,15); x1^=x0;
  x0+=x1; x1=rotl32(x1,26); x1^=x0;
  x0+=x1; x1=rotl32(x1, 6); x1^=x0;
  x0+=k2; x1+=k0+5u;
  return K2{x0,x1};
}
static_assert(tf2x32(0u,0u,0u,2u).a==4146024105u, "threefry mismatch o0");
static_assert(tf2x32(0u,0u,0u,2u).b==2718843009u, "threefry mismatch o1");
static_assert(tf2x32(0u,0u,1u,3u).a==967050713u,  "threefry mismatch o0b");
static_assert(tf2x32(0u,0u,1u,3u).b==1272950319u, "threefry mismatch o1b");

// partitionable threefry (verified passing r4-r14)
constexpr K2 E0 = tf2x32(0u,42u,0u,0u);     // key1
constexpr K2 E1 = tf2x32(0u,42u,0u,1u);     // sub1
constexpr unsigned SK1A = E1.a, SK1B = E1.b;
constexpr K2 F1 = tf2x32(E0.a,E0.b,0u,1u);  // sub2
constexpr unsigned SK2A = F1.a, SK2B = F1.b;

// med buffer: [0]=hstar [1]=base [2]=cnt [3]=lo_cut [4]=rk_cut ; [8..71]=lo, [72..135]=rk
#define MED_CAP 64

// LDS row stride for GEMM tiles: 40 shorts (80B) -> bank walk 20*row mod 32 (2-way max)
#define LDW 40

// ---------------- weight transpose helper ----------------
__device__ inline void tconv(const float* __restrict__ src, unsigned short* __restrict__ dst,
                             int R, int C, int r0, int c0){
  __shared__ unsigned short tile[64][72];
  int t = threadIdx.x;
  int tr = t>>2, tc = (t&3)*16;
  #pragma unroll
  for (int u=0;u<16;u++)
    tile[tr][tc+u] = bf16rne(src[(size_t)(r0+tr)*C + c0 + tc + u]);
  __syncthreads();
  unsigned short v[16];
  #pragma unroll
  for (int u=0;u<16;u++) v[u] = tile[tc+u][tr];
  uint4* vv = (uint4*)v;
  uint4* o = (uint4*)&dst[(size_t)(c0+tr)*R + r0 + tc];
  o[0] = vv[0]; o[1] = vv[1];
}

// ---------------- front: edges (0..511) + x tiles (512..767) + weights ----------------
__global__ void front_k(const int* __restrict__ ei,
                        unsigned* __restrict__ keys1, unsigned* __restrict__ keys2,
                        unsigned* __restrict__ hist1, unsigned* __restrict__ hist2,
                        unsigned* __restrict__ indeg, unsigned* __restrict__ outdeg,
                        unsigned* __restrict__ bits,
                        const float* __restrict__ x, unsigned short* __restrict__ x_bf,
                        unsigned short* __restrict__ xT_bf,
                        const float* __restrict__ W0, unsigned short* __restrict__ WT0,
                        const float* __restrict__ W1, unsigned short* __restrict__ WT1,
                        const float* __restrict__ W2, unsigned short* __restrict__ WT2,
                        const float* __restrict__ fcW, unsigned short* __restrict__ fcWT){
  int b = blockIdx.x, t = threadIdx.x;
  if (b < 512){
    unsigned e = b*256u + t;
    K2 r1 = tf2x32(SK1A, SK1B, 0u, e);
    unsigned k1 = r1.a ^ r1.b;
    K2 r2 = tf2x32(SK2A, SK2B, 0u, e);
    unsigned k2 = r2.a ^ r2.b;
    keys1[e] = k1; keys2[e] = k2;
    atomicAdd(&hist1[k1>>16], 1u);
    atomicAdd(&hist2[k2>>16], 1u);
    unsigned s = (unsigned)ei[e], d = (unsigned)ei[NE+e];
    atomicAdd(&outdeg[s], 1u);
    atomicAdd(&indeg[d], 1u);
    atomicOr(&bits[d*128 + (s>>5)], 1u << (s&31));
    if (e < NN) atomicOr(&bits[e*128 + (e>>5)], 1u << (e&31));
    return;
  }
  int b2 = b - 512;
  if (b2 < 256){                                        // x tile: emit x_bf + xT_bf
    __shared__ unsigned short tile[64][72];
    int r0 = (b2>>2)*64, c0 = (b2&3)*64;
    int tr = t>>2, tc = (t&3)*16;
    #pragma unroll
    for (int u=0;u<16;u++)
      tile[tr][tc+u] = bf16rne(x[(size_t)(r0+tr)*DIN + c0 + tc + u]);
    __syncthreads();
    unsigned short vr[16];
    #pragma unroll
    for (int u=0;u<16;u++) vr[u] = tile[tr][tc+u];
    uint4* rv = (uint4*)vr;
    uint4* xo = (uint4*)&x_bf[(size_t)(r0+tr)*DIN + c0 + tc];
    xo[0] = rv[0]; xo[1] = rv[1];
    unsigned short v[16];
    #pragma unroll
    for (int u=0;u<16;u++) v[u] = tile[tc+u][tr];
    uint4* vv = (uint4*)v;
    uint4* o = (uint4*)&xT_bf[(size_t)(c0+tr)*NN + r0 + tc];
    o[0] = vv[0]; o[1] = vv[1];
  } else if (b2 < 352){                                 // 3 enc weights: 32 tiles each
    int idx = b2 - 256;
    int z = idx >> 5, tl = idx & 31;
    const float* src = z==0?W0 : z==1?W1 : W2;
    unsigned short* dst = z==0?WT0 : z==1?WT1 : WT2;
    tconv(src, dst, DIN, DHID, (tl>>3)*64, (tl&7)*64);
  } else {                                              // fcW: 24 tiles
    int by = b2 - 352;
    tconv(fcW, fcWT, DCAT, DOUT, by*64, 0);
  }
}

// ---------------- single-launch quad scan (wave-parallel decoupled lookback) + med1 ----------------
__global__ void scanAll_k(const unsigned* __restrict__ in0, const unsigned* __restrict__ in1,
                          const unsigned* __restrict__ in2, const unsigned* __restrict__ in3,
                          unsigned* __restrict__ o0, unsigned* __restrict__ o1,
                          unsigned* __restrict__ o2, unsigned* __restrict__ o3,
                          unsigned* __restrict__ c0, unsigned* __restrict__ c1,
                          unsigned* __restrict__ c2, unsigned* __restrict__ c3,
                          unsigned* __restrict__ flags, const unsigned* __restrict__ hist2,
                          unsigned* __restrict__ med){
  int y = blockIdx.y;
  int nblk = (y<2) ? (NBINS/256) : (NN/256);
  int xb = blockIdx.x;
  if (xb >= nblk) return;
  const unsigned* in = y==0?in0 : y==1?in1 : y==2?in2 : in3;
  unsigned* o        = y==0?o0  : y==1?o1  : y==2?o2  : o3;
  unsigned* c        = y==0?c0  : y==1?c1  : y==2?c2  : c3;
  __shared__ unsigned s[256];
  __shared__ unsigned base_s;
  int t = threadIdx.x; unsigned i = xb*256u + t;
  unsigned v = in[i]; s[t] = v; __syncthreads();
  for (int off=1; off<256; off<<=1){
    unsigned u = (t>=off)?s[t-off]:0u; __syncthreads();
    s[t]+=u; __syncthreads();
  }
  unsigned excl = s[t]-v;
  unsigned total = s[255];
  unsigned* f = flags + y*256;
  if (xb == 0){
    if (t==0){ atomicExch(&f[0], 0x80000000u | total); base_s = 0u; }
  } else {
    if (t==0) atomicExch(&f[xb], 0x40000000u | total);
    if (t < 64){
      unsigned base = 0; int start = xb-1; int done = 0;
      while (!done && start >= 0){
        int idx = start - t;
        unsigned fv = 0;
        if (idx >= 0){
          do { fv = atomicAdd(&f[idx], 0u); } while (!(fv & 0xC0000000u));
        }
        unsigned long long pm = __ballot(idx >= 0 && (fv & 0x80000000u));
        unsigned contrib;
        if (pm){
          int plane = __ffsll((long long)pm) - 1;
          contrib = (idx >= 0 && t <= plane) ? (fv & 0x3FFFFFFFu) : 0u;
          done = 1;
        } else {
          contrib = (idx >= 0) ? (fv & 0x3FFFFFFFu) : 0u;
          start -= 64;
        }
        for (int oo=32; oo>0; oo>>=1) contrib += __shfl_xor(contrib, oo, 64);
        base += contrib;
      }
      if (t==0){ atomicExch(&f[xb], 0x80000000u | (base + total)); base_s = base; }
    }
  }
  __syncthreads();
  unsigned res = excl + base_s;
  o[i] = res; c[i] = res;
  if (y==1){
    unsigned hv = hist2[i];
    if (res <= HALF_E && HALF_E < res + hv){ med[0] = i; med[1] = res; }
  }
}

// ---------------- scat1 (packed u64 payload) + median-bin collection ----------------
__global__ void scat1med_k(const unsigned* __restrict__ keys1, const unsigned* __restrict__ keys2,
                           unsigned* __restrict__ cursor, unsigned long long* __restrict__ slowstb,
                           unsigned* __restrict__ med){
  int e = blockIdx.x*256 + threadIdx.x;
  unsigned k = keys1[e];
  unsigned p = atomicAdd(&cursor[k>>16], 1u);
  slowstb[p] = ((unsigned long long)(k & 0xFFFFu) << 32) | (unsigned)e;
  unsigned k2 = keys2[e];
  if ((k2>>16) == med[0]){
    unsigned idx = atomicAdd(&med[2], 1u);
    if (idx < MED_CAP){ med[8+idx] = k2 & 0xFFFFu; med[72+idx] = (unsigned)e; }
  }
}

// ---------------- rank1 + CSR scatter (blocks 0..EB-1) + med3 cut-selection (block EB) ----------------
__global__ void rankscat_k(const int* __restrict__ ei, const unsigned* __restrict__ keys1,
                           const unsigned* __restrict__ prefix, const unsigned* __restrict__ hist,
                           const unsigned long long* __restrict__ slowstb,
                           unsigned* __restrict__ curin, unsigned* __restrict__ curout,
                           unsigned* __restrict__ in_list, unsigned* __restrict__ out_list,
                           unsigned* __restrict__ med){
  int b = blockIdx.x, t = threadIdx.x;
  if (b == NE/256){
    unsigned n = med[2]; if (n > MED_CAP) n = MED_CAP;
    unsigned qcut = HALF_E - med[1];
    if (t < (int)n){
      unsigned lo = med[8+t], rk = med[72+t], pos = 0;
      for (unsigned j=0;j<n;j++){
        unsigned lj = med[8+j], rj = med[72+j];
        if (lj < lo || (lj==lo && rj < rk)) pos++;
      }
      if (pos == qcut){ med[3] = lo; med[4] = rk; }
    }
    return;
  }
  int e = b*256 + t;
  unsigned k = keys1[e], h = k>>16;
  unsigned long long me = ((unsigned long long)(k & 0xFFFFu) << 32) | (unsigned)e;
  unsigned base = prefix[h], n = hist[h], r = 0;
  for (unsigned j=0;j<n;j++)
    r += (slowstb[base+j] < me) ? 1u : 0u;
  unsigned rk = base + r;
  unsigned s = (unsigned)ei[e], d = (unsigned)ei[NE+e];
  unsigned p = atomicAdd(&curin[d], 1u);  in_list[p] = s;
  unsigned q = atomicAdd(&curout[s], 1u); out_list[q] = d | (rk<<12);
}

// ---------------- reach (blocks 0..NN-1) + cut (NN..2NN-1): 4-group vectorized gathers ----------------
__global__ void reachcut_k(const unsigned* __restrict__ bits, const unsigned* __restrict__ in_off,
                           const unsigned* __restrict__ in_list, const unsigned* __restrict__ indeg,
                           unsigned* __restrict__ reach, float* __restrict__ cntinv,
                           const float* __restrict__ x, const unsigned* __restrict__ out_off,
                           const unsigned* __restrict__ outdeg, const unsigned* __restrict__ out_list,
                           const unsigned* __restrict__ keys2, const unsigned* __restrict__ med,
                           unsigned short* __restrict__ cut_bf){
  __shared__ unsigned nbr[256];
  int b = blockIdx.x, t = threadIdx.x;
  int g = t>>6, l = t&63;
  if (b < NN){
    __shared__ unsigned combA[4][64], combB[4][64];
    int i = b;
    unsigned off = in_off[i], deg = indeg[i];
    unsigned a0=0u, a1=0u;
    if (g==0){ uint2 sb = *(const uint2*)&bits[(size_t)i*128 + l*2]; a0=sb.x; a1=sb.y; }
    for (unsigned base=0; base<deg; base+=256){
      unsigned ch = min(deg-base, 256u);
      if (t < (int)ch) nbr[t] = in_list[off+base+t];
      __syncthreads();
      for (unsigned j=g; j<ch; j+=4){
        uint2 v = *(const uint2*)&bits[(size_t)nbr[j]*128 + l*2];
        a0 |= v.x; a1 |= v.y;
      }
      __syncthreads();
    }
    combA[g][l]=a0; combB[g][l]=a1;
    __syncthreads();
    if (g==0){
      a0 |= combA[1][l] | combA[2][l] | combA[3][l];
      a1 |= combB[1][l] | combB[2][l] | combB[3][l];
      uint2 o; o.x=a0; o.y=a1;
      *(uint2*)&reach[(size_t)i*128 + l*2] = o;
      int c = __popc(a0) + __popc(a1);
      for (int oo=32;oo>0;oo>>=1) c += __shfl_xor(c, oo, 64);
      if (l==0) cntinv[i] = 1.0f / (float)c;
    }
  } else {
    __shared__ unsigned key_s[256];
    __shared__ float4 combF[4][64];
    __shared__ int combC[4];
    int s = b - NN;
    unsigned off = out_off[s], deg = outdeg[s];
    unsigned hs = med[0], loc = med[3], rkc = med[4];
    float4 acc = {0.f,0.f,0.f,0.f}; int cnt = 0;
    for (unsigned base=0; base<deg; base+=256){
      unsigned ch = min(deg-base, 256u);
      if (t < (int)ch){
        unsigned v = out_list[off+base+t];
        nbr[t] = v;
        key_s[t] = keys2[v >> 12];
      }
      __syncthreads();
      for (unsigned j=g; j<ch; j+=4){
        unsigned v = nbr[j], k2 = key_s[j];
        unsigned rk = v >> 12;
        unsigned h = k2>>16, lo = k2 & 0xFFFFu;
        unsigned keep = (h > hs) || (h == hs && (lo > loc || (lo == loc && rk >= rkc)));
        if (keep){
          cnt++;
          float4 xv = *(const float4*)&x[(size_t)(v & 0xFFFu)*DIN + l*4];
          acc.x += xv.x; acc.y += xv.y; acc.z += xv.z; acc.w += xv.w;
        }
      }
      __syncthreads();
    }
    combF[g][l] = acc;
    if (l==0) combC[g] = cnt;
    __syncthreads();
    if (g==0){
      float4 a1 = combF[1][l], a2 = combF[2][l], a3 = combF[3][l];
      float sx = acc.x+a1.x+a2.x+a3.x, sy = acc.y+a1.y+a2.y+a3.y;
      float sz = acc.z+a1.z+a2.z+a3.z, sw = acc.w+a1.w+a2.w+a3.w;
      int c = combC[0]+combC[1]+combC[2]+combC[3];
      float vx, vy, vz, vw;
      if (c){ float ci = 1.0f/(float)c; vx=sx*ci; vy=sy*ci; vz=sz*ci; vw=sw*ci; }
      else { float4 xv = *(const float4*)&x[(size_t)s*DIN + l*4]; vx=xv.x; vy=xv.y; vz=xv.z; vw=xv.w; }
      uint2 o;
      o.x = (unsigned)bf16rne(vx) | ((unsigned)bf16rne(vy)<<16);
      o.y = (unsigned)bf16rne(vz) | ((unsigned)bf16rne(vw)<<16);
      *(uint2*)&cut_bf[(size_t)s*DIN + l*4] = o;
    }
  }
}

// ---------------- ego bit-GEMM, BN=128, split-K=4, K_STEP=128, stride-40 LDS ----------------
// grid (NN/64, DIN/128, 4) = (64, 2, 4); 8 MFMA per A-expansion (VALU:MFMA ~1:1)
__global__ void bitgemm_k(const unsigned* __restrict__ reach, const unsigned short* __restrict__ xT,
                          float* __restrict__ pbuf){
  __shared__ __align__(16) unsigned short bt[4][128*LDW];   // 40 KB
  int t = threadIdx.x, w = t>>6, l = t&63;
  int m0 = blockIdx.x*64, n0 = blockIdx.y*128;
  int kbase = blockIdx.z*(NN/4);
  int srow = t>>1, sq = (t&1)*16;        // row 0..127, short offset 0/16
  int arow = m0 + 16*w + (l&15);
  int lg = l>>4;
  f32x4 acc[8];
  #pragma unroll
  for (int c=0;c<8;c++) acc[c] = f32x4{0.f,0.f,0.f,0.f};

  for (int it=0; it<8; ++it){
    int kk = kbase + it*128;
    __syncthreads();
    #pragma unroll
    for (int s=0;s<4;s++){
      const unsigned short* src = &xT[(size_t)(n0+srow)*NN + kk + 32*s + sq];
      uint4 v0 = *(const uint4*)src;
      uint4 v1 = *(const uint4*)(src+8);
      *(uint4*)&bt[s][srow*LDW + sq]     = v0;
      *(uint4*)&bt[s][srow*LDW + sq + 8] = v1;
    }
    __syncthreads();
    unsigned rw[4];
    *(uint4*)rw = *(const uint4*)&reach[(size_t)arow*128 + (kk>>5)];
    #pragma unroll
    for (int s=0;s<4;s++){
      unsigned byte = (rw[s] >> (8*lg)) & 0xFFu;
      union { short8 s8; unsigned u[4]; } af;
      #pragma unroll
      for (int pp=0;pp<4;pp++){
        unsigned b0 = (byte>>(2*pp))&1u, b1 = (byte>>(2*pp+1))&1u;
        af.u[pp] = b0*0x3F80u | b1*0x3F800000u;
      }
      #pragma unroll
      for (int c=0;c<8;c++){
        int brow = 16*c + (l&15);
        short8 bf = *(const short8*)&bt[s][brow*LDW + lg*8];
        acc[c] = __builtin_amdgcn_mfma_f32_16x16x32_bf16(af.s8, bf, acc[c], 0,0,0);
      }
    }
  }
  size_t zoff = (size_t)blockIdx.z*NN*DIN;
  #pragma unroll
  for (int c=0;c<8;c++){
    #pragma unroll
    for (int r=0;r<4;r++){
      int row = m0 + 16*w + 4*lg + r;
      int col = n0 + 16*c + (l&15);
      pbuf[zoff + (size_t)row*DIN + col] = acc[c][r];
    }
  }
}

// ---------------- reduce partials + scale -> ego_bf ----------------
__global__ void redscale_k(const float* __restrict__ pbuf, const float* __restrict__ cntinv,
                           unsigned short* __restrict__ ego_bf){
  int g = blockIdx.x*256 + threadIdx.x;
  const size_t S = (size_t)NN*DIN/4;
  const float4* p4 = (const float4*)pbuf;
  float4 a = p4[g], b = p4[g+S], c = p4[g+2*S], d = p4[g+3*S];
  int row = (g*4)>>8;
  float ci = cntinv[row];
  float vx = (a.x+b.x+c.x+d.x)*ci, vy = (a.y+b.y+c.y+d.y)*ci;
  float vz = (a.z+b.z+c.z+d.z)*ci, vw = (a.w+b.w+c.w+d.w)*ci;
  uint2 o;
  o.x = (unsigned)bf16rne(vx) | ((unsigned)bf16rne(vy)<<16);
  o.y = (unsigned)bf16rne(vz) | ((unsigned)bf16rne(vw)<<16);
  ((uint2*)ego_bf)[g] = o;
}

// ---------------- aggregate features over in-edges: 4-group vectorized ----------------
__global__ void aggfeat_k(const unsigned short* __restrict__ ego_bf, const unsigned short* __restrict__ cut_bf,
                          const unsigned* __restrict__ in_off, const unsigned* __restrict__ indeg,
                          const unsigned* __restrict__ in_list,
                          unsigned short* __restrict__ aggE, unsigned short* __restrict__ aggC){
  __shared__ unsigned nbr[256];
  __shared__ float4 combE[4][64], combD[4][64];
  int i = blockIdx.x, t = threadIdx.x;
  int g = t>>6, l = t&63;
  unsigned off = in_off[i], deg = indeg[i];
  float4 ae = {0.f,0.f,0.f,0.f}, ac = {0.f,0.f,0.f,0.f};
  for (unsigned base=0; base<deg; base+=256){
    unsigned ch = min(deg-base, 256u);
    if (t < (int)ch) nbr[t] = in_list[off+base+t];
    __syncthreads();
    for (unsigned j=g; j<ch; j+=4){
      unsigned s = nbr[j];
      uint2 ev = *(const uint2*)&ego_bf[(size_t)s*DIN + l*4];
      uint2 cv = *(const uint2*)&cut_bf[(size_t)s*DIN + l*4];
      ae.x += bf2f((unsigned short)(ev.x & 0xFFFFu));
      ae.y += bf2f((unsigned short)(ev.x >> 16));
      ae.z += bf2f((unsigned short)(ev.y & 0xFFFFu));
      ae.w += bf2f((unsigned short)(ev.y >> 16));
      ac.x += bf2f((unsigned short)(cv.x & 0xFFFFu));
      ac.y += bf2f((unsigned short)(cv.x >> 16));
      ac.z += bf2f((unsigned short)(cv.y & 0xFFFFu));
      ac.w += bf2f((unsigned short)(cv.y >> 16));
    }
    __syncthreads();
  }
  combE[g][l] = ae; combD[g][l] = ac;
  __syncthreads();
  if (g==0){
    float4 e1 = combE[1][l], e2 = combE[2][l], e3 = combE[3][l];
    float4 c1 = combD[1][l], c2 = combD[2][l], c3 = combD[3][l];
    float ex = ae.x+e1.x+e2.x+e3.x, ey = ae.y+e1.y+e2.y+e3.y;
    float ez = ae.z+e1.z+e2.z+e3.z, ew = ae.w+e1.w+e2.w+e3.w;
    float cx = ac.x+c1.x+c2.x+c3.x, cy = ac.y+c1.y+c2.y+c3.y;
    float cz = ac.z+c1.z+c2.z+c3.z, cw = ac.w+c1.w+c2.w+c3.w;
    uint2 oe, oc;
    oe.x = (unsigned)bf16rne(ex) | ((unsigned)bf16rne(ey)<<16);
    oe.y = (unsigned)bf16rne(ez) | ((unsigned)bf16rne(ew)<<16);
    oc.x = (unsigned)bf16rne(cx) | ((unsigned)bf16rne(cy)<<16);
    oc.y = (unsigned)bf16rne(cz) | ((unsigned)bf16rne(cw)<<16);
    *(uint2*)&aggE[(size_t)i*DIN + l*4] = oe;
    *(uint2*)&aggC[(size_t)i*DIN + l*4] = oc;
  }
}

// ---------------- merged encoder GEMM (z: 0=ego-agg,1=cut-agg,2=glob), stride-40 LDS ----------------
__global__ void gemm3_k(const unsigned short* __restrict__ aggE, const unsigned short* __restrict__ aggC,
                        const unsigned short* __restrict__ xbf,
                        const unsigned short* __restrict__ WTe, const unsigned short* __restrict__ WTc,
                        const unsigned short* __restrict__ WTg,
                        const float* __restrict__ eb, const float* __restrict__ cb, const float* __restrict__ gb,
                        const unsigned* __restrict__ indeg, unsigned short* __restrict__ hcat){
  __shared__ __align__(16) unsigned short at[4][64*LDW];
  __shared__ __align__(16) unsigned short bt[4][64*LDW];
  int z = blockIdx.z;
  const unsigned short* A  = z==0? aggE : z==1? aggC : xbf;
  const unsigned short* BT = z==0? WTe  : z==1? WTc  : WTg;
  const float* bias        = z==0? eb   : z==1? cb   : gb;
  int t = threadIdx.x, w = t>>6, l = t&63;
  int n0 = blockIdx.x*64, m0 = blockIdx.y*64;
  int srow = t>>2, sg = t&3;
  int lg = l>>4;
  f32x4 acc[4];
  #pragma unroll
  for (int c=0;c<4;c++) acc[c] = f32x4{0.f,0.f,0.f,0.f};

  for (int it=0; it<2; ++it){
    int kk = it*128;
    __syncthreads();
    #pragma unroll
    for (int s=0;s<4;s++){
      uint4 va = *(const uint4*)&A [(size_t)(m0+srow)*DIN + kk + 32*s + sg*8];
      uint4 vb = *(const uint4*)&BT[(size_t)(n0+srow)*DIN + kk + 32*s + sg*8];
      *(uint4*)&at[s][srow*LDW + sg*8] = va;
      *(uint4*)&bt[s][srow*LDW + sg*8] = vb;
    }
    __syncthreads();
    int ar = 16*w + (l&15);
    #pragma unroll
    for (int s=0;s<4;s++){
      short8 af = *(const short8*)&at[s][ar*LDW + lg*8];
      #pragma unroll
      for (int c=0;c<4;c++){
        int brow = 16*c + (l&15);
        short8 bf = *(const short8*)&bt[s][brow*LDW + lg*8];
        acc[c] = __builtin_amdgcn_mfma_f32_16x16x32_bf16(af, bf, acc[c], 0,0,0);
      }
    }
  }
  #pragma unroll
  for (int c=0;c<4;c++){
    #pragma unroll
    for (int r=0;r<4;r++){
      int row = m0 + 16*w + 4*lg + r;
      int col = n0 + 16*c + (l&15);
      float scale = (z<2) ? (float)indeg[row] : 1.0f;
      float v = acc[c][r] + bias[col]*scale;
      if (z<2) v = fmaxf(v, 0.f);
      hcat[(size_t)row*DCAT + z*DHID + col] = bf16rne(v);
    }
  }
}

// ---------------- fc GEMM full-K + fused bias + log_softmax, stride-40 LDS ----------------
__global__ void fcsm_k(const unsigned short* __restrict__ hcat, const unsigned short* __restrict__ fcWT,
                       const float* __restrict__ fcb, float* __restrict__ out){
  __shared__ __align__(16) unsigned short at[4][64*LDW];
  __shared__ __align__(16) unsigned short bt[4][64*LDW];
  int t = threadIdx.x, w = t>>6, l = t&63;
  int m0 = blockIdx.x*64;
  int srow = t>>2, sg = t&3;
  int lg = l>>4;
  f32x4 acc[4];
  #pragma unroll
  for (int c=0;c<4;c++) acc[c] = f32x4{0.f,0.f,0.f,0.f};

  for (int it=0; it<12; ++it){
    int kk = it*128;
    __syncthreads();
    #pragma unroll
    for (int s=0;s<4;s++){
      uint4 va = *(const uint4*)&hcat [(size_t)(m0+srow)*DCAT + kk + 32*s + sg*8];
      uint4 vb = *(const uint4*)&fcWT[(size_t)srow*DCAT + kk + 32*s + sg*8];
      *(uint4*)&at[s][srow*LDW + sg*8] = va;
      *(uint4*)&bt[s][srow*LDW + sg*8] = vb;
    }
    __syncthreads();
    int ar = 16*w + (l&15);
    #pragma unroll
    for (int s=0;s<4;s++){
      short8 af = *(const short8*)&at[s][ar*LDW + lg*8];
      #pragma unroll
      for (int c=0;c<4;c++){
        int brow = 16*c + (l&15);
        short8 bf = *(const short8*)&bt[s][brow*LDW + lg*8];
        acc[c] = __builtin_amdgcn_mfma_f32_16x16x32_bf16(af, bf, acc[c], 0,0,0);
      }
    }
  }
  #pragma unroll
  for (int r=0;r<4;r++){
    int row = m0 + 16*w + 4*lg + r;
    float v0 = acc[0][r] + fcb[(l&15)];
    float v1 = acc[1][r] + fcb[16 + (l&15)];
    float v2 = acc[2][r] + fcb[32 + (l&15)];
    float v3 = acc[3][r] + fcb[48 + (l&15)];
    float m = fmaxf(fmaxf(v0,v1), fmaxf(v2,v3));
    m = fmaxf(m, __shfl_xor(m, 1, 64));
    m = fmaxf(m, __shfl_xor(m, 2, 64));
    m = fmaxf(m, __shfl_xor(m, 4, 64));
    m = fmaxf(m, __shfl_xor(m, 8, 64));
    float s = __expf(v0-m) + __expf(v1-m) + __expf(v2-m) + __expf(v3-m);
    s += __shfl_xor(s, 1, 64);
    s += __shfl_xor(s, 2, 64);
    s += __shfl_xor(s, 4, 64);
    s += __shfl_xor(s, 8, 64);
    float ls = logf(s);
    size_t ro = (size_t)row*DOUT + (l&15);
    out[ro]      = (v0 - m) - ls;
    out[ro + 16] = (v1 - m) - ls;
    out[ro + 32] = (v2 - m) - ls;
    out[ro + 48] = (v3 - m) - ls;
  }
}

// ---------------- host launch ----------------
static inline size_t alignup(size_t x){ return (x + 255) & ~(size_t)255; }

extern "C" void kernel_launch(void* const* d_in, const int* in_sizes, int n_in,
                              void* d_out, int out_size, void* d_ws, size_t ws_size,
                              hipStream_t stream) {
  const float* x      = (const float*)d_in[0];
  const int*   ei     = (const int*)  d_in[1];
  const float* ego_W  = (const float*)d_in[2];
  const float* ego_b  = (const float*)d_in[3];
  const float* cut_W  = (const float*)d_in[4];
  const float* cut_b  = (const float*)d_in[5];
  const float* glob_W = (const float*)d_in[6];
  const float* glob_b = (const float*)d_in[7];
  const float* fc_W   = (const float*)d_in[8];
  const float* fc_b   = (const float*)d_in[9];
  float* out = (float*)d_out;

  char* base = (char*)d_ws;
  char* p = base;
  #define ALLOC(ty, name, cnt) ty* name = (ty*)p; p += alignup(sizeof(ty)*(size_t)(cnt));
  ALLOC(char,           R0,      (size_t)4*NN*DIN*4);   // 16MB: sort temps -> pbuf -> hcat
  // ---- zero region (one memset) ----
  ALLOC(unsigned,       bits,    NN*128);
  ALLOC(unsigned,       indeg,   NN);
  ALLOC(unsigned,       outdeg,  NN);
  ALLOC(unsigned,       hist1,   NBINS);
  ALLOC(unsigned,       hist2,   NBINS);
  ALLOC(unsigned,       med,     256);
  ALLOC(unsigned,       flags,   1024);
  char* zero_end = p;
  // ---- rest ----
  ALLOC(unsigned,       in_off,  NN);
  ALLOC(unsigned,       out_off, NN);
  ALLOC(unsigned,       curin,   NN);
  ALLOC(unsigned,       curout,  NN);
  ALLOC(unsigned,       in_list, NE);
  ALLOC(unsigned,       out_list,NE);
  ALLOC(unsigned,       reach,   NN*128);
  ALLOC(float,          cntinv,  NN);
  ALLOC(unsigned short, x_bf,    (size_t)NN*DIN);
  ALLOC(unsigned short, xT_bf,   (size_t)DIN*NN);
  ALLOC(unsigned short, ego_bf,  (size_t)NN*DIN);
  ALLOC(unsigned short, cut_bf,  (size_t)NN*DIN);
  ALLOC(unsigned short, aggE_bf, (size_t)NN*DIN);
  ALLOC(unsigned short, aggC_bf, (size_t)NN*DIN);
  ALLOC(unsigned short, egoWT,   (size_t)DHID*DIN);
  ALLOC(unsigned short, cutWT,   (size_t)DHID*DIN);
  ALLOC(unsigned short, globWT,  (size_t)DHID*DIN);
  ALLOC(unsigned short, fcWT,    (size_t)DOUT*DCAT);
  ALLOC(unsigned,       prefix1, NBINS);
  ALLOC(unsigned,       cursor1, NBINS);
  ALLOC(unsigned,       prefix2, NBINS);
  ALLOC(unsigned,       cursor2, NBINS);
  #undef ALLOC
  size_t need = (size_t)(p - base);
  if (ws_size < need){
    hipMemsetAsync(d_out, 0x7F, (size_t)out_size*sizeof(float), stream);
    return;
  }
  float*          pbuf = (float*)R0;
  unsigned short* hcat = (unsigned short*)R0;
  char* q = R0;
  #define OALLOC(ty, name, cnt) ty* name = (ty*)q; q += alignup(sizeof(ty)*(size_t)(cnt));
  OALLOC(unsigned,            keys1,   NE);
  OALLOC(unsigned,            keys2,   NE);
  OALLOC(unsigned long long,  slowstb, NE);
  #undef OALLOC

  const int EB = NE/256;

  // 1) zero [bits|indeg|outdeg|hist1|hist2|med|flags]
  hipMemsetAsync(bits, 0, (size_t)(zero_end - (char*)bits), stream);
  // 2) keys + hists + degrees + bits + ALL conversions
  hipLaunchKernelGGL(front_k, dim3(888), dim3(256), 0, stream,
                     ei, keys1, keys2, hist1, hist2, indeg, outdeg, bits,
                     x, x_bf, xT_bf, ego_W, egoWT, cut_W, cutWT, glob_W, globWT, fc_W, fcWT);
  // 3) quad scan (wave-parallel lookback) + median-bin locate
  hipLaunchKernelGGL(scanAll_k, dim3(NBINS/256, 4), dim3(256), 0, stream,
                     hist1, hist2, indeg, outdeg,
                     prefix1, prefix2, in_off, out_off,
                     cursor1, cursor2, curin, curout, flags, hist2, med);
  // 4) round-1 binned scatter (packed payload) + median-bin member collection
  hipLaunchKernelGGL(scat1med_k, dim3(EB), dim3(256), 0, stream,
                     keys1, keys2, cursor1, slowstb, med);
  // 5) round-1 rank + CSR scatter (rk packed in out_list) + cut-element selection
  hipLaunchKernelGGL(rankscat_k, dim3(EB+1), dim3(256), 0, stream,
                     ei, keys1, prefix1, hist1, slowstb, curin, curout, in_list, out_list, med);
  // 6) 2-hop reach + cut feature (4-group vectorized, inline keep)
  hipLaunchKernelGGL(reachcut_k, dim3(2*NN), dim3(256), 0, stream,
                     bits, in_off, in_list, indeg, reach, cntinv,
                     x, out_off, outdeg, out_list, keys2, med, cut_bf);
  // 7) ego bit-GEMM, BN=128 (pbuf overlays sort temps; keys dead after step 6)
  hipLaunchKernelGGL(bitgemm_k, dim3(NN/64, DIN/128, 4), dim3(256), 0, stream, reach, xT_bf, pbuf);
  // 8) reduce partials + scale
  hipLaunchKernelGGL(redscale_k, dim3((NN*DIN/4)/256), dim3(256), 0, stream, pbuf, cntinv, ego_bf);
  // 9) feature aggregation (4-group vectorized)
  hipLaunchKernelGGL(aggfeat_k, dim3(NN), dim3(256), 0, stream,
                     ego_bf, cut_bf, in_off, indeg, in_list, aggE_bf, aggC_bf);
  // 10) encoders -> hcat (overlays pbuf, dead after 8)
  hipLaunchKernelGGL(gemm3_k, dim3(DHID/64, NN/64, 3), dim3(256), 0, stream,
                     aggE_bf, aggC_bf, x_bf, egoWT, cutWT, globWT,
                     ego_b, cut_b, glob_b, indeg, hcat);
  // 11) fc full-K + fused bias + log_softmax
  hipLaunchKernelGGL(fcsm_k, dim3(NN/64), dim3(256), 0, stream, hcat, fcWT, fc_b, out);
}

// Round 16
// 154.899 us; speedup vs baseline: 1.0899x; 1.0899x over previous
//
#include <hip/hip_runtime.h>

#define NN 4096
#define NE 131072
#define DIN 256
#define DHID 512
#define DOUT 64
#define DCAT 1536
#define NBINS 65536
#define HALF_E 65536

typedef __attribute__((ext_vector_type(8))) short short8;
typedef __attribute__((ext_vector_type(4))) float f32x4;

__device__ inline unsigned short bf16rne(float f){
  unsigned u = __float_as_uint(f);
  unsigned r = u + 0x7FFFu + ((u>>16)&1u);
  return (unsigned short)(r>>16);
}
__device__ inline float bf2f(unsigned short u){ return __uint_as_float(((unsigned)u)<<16); }

// ---------------- Threefry-2x32 (JAX-compatible) ----------------
struct K2 { unsigned a, b; };
__host__ __device__ constexpr unsigned rotl32(unsigned x, unsigned d){ return (x<<d)|(x>>(32u-d)); }
__host__ __device__ constexpr K2 tf2x32(unsigned k0, unsigned k1, unsigned x0, unsigned x1){
  unsigned k2 = k0 ^ k1 ^ 0x1BD11BDAu;
  x0 += k0; x1 += k1;
  x0+=x1; x1=rotl32(x1,13); x1^=x0;
  x0+=x1; x1=rotl32(x1,15); x1^=x0;
  x0+=x1; x1=rotl32(x1,26); x1^=x0;
  x0+=x1; x1=rotl32(x1, 6); x1^=x0;
  x0+=k1; x1+=k2+1u;
  x0+=x1; x1=rotl32(x1,17); x1^=x0;
  x0+=x1; x1=rotl32(x1,29); x1^=x0;
  x0+=x1; x1=rotl32(x1,16); x1^=x0;
  x0+=x1; x1=rotl32(x1,24); x1^=x0;
  x0+=k2; x1+=k0+2u;
  x0+=x1; x1=rotl32(x1,13); x1^=x0;
  x0+=x1; x1=rotl32(x1,15); x1^=x0;
  x0+=x1; x1=rotl32(x1,26); x1^=x0;
  x0+=x1; x1=rotl32(x1, 6); x1^=x0;
  x0+=k0; x1+=k1+3u;
  x0+=x1; x1=rotl32(x1,17); x1^=x0;
  x0+=x1; x1=rotl32(x1,29); x1^=x0;
  x0+=x1; x1=rotl32(x1,16); x1^=x0;
  x0+=x1; x1=rotl32(x1,24); x1^=x0;
  x0+=k1; x1+=k2+4u;
  x0+=x1; x1=rotl32(x1,13); x1^=x0;
  x0+=x1; x1=rotl32(x1,15); x1^=x0;
  x0+=x1; x1=rotl32(x1,26); x1^=x0;
  x0+=x1; x1=rotl32(x1, 6); x1^=x0;
  x0+=k2; x1+=k0+5u;
  return K2{x0,x1};
}
static_assert(tf2x32(0u,0u,0u,2u).a==4146024105u, "threefry mismatch o0");
static_assert(tf2x32(0u,0u,0u,2u).b==2718843009u, "threefry mismatch o1");
static_assert(tf2x32(0u,0u,1u,3u).a==967050713u,  "threefry mismatch o0b");
static_assert(tf2x32(0u,0u,1u,3u).b==1272950319u, "threefry mismatch o1b");

// partitionable threefry (verified passing r4-r15)
constexpr K2 E0 = tf2x32(0u,42u,0u,0u);     // key1
constexpr K2 E1 = tf2x32(0u,42u,0u,1u);     // sub1
constexpr unsigned SK1A = E1.a, SK1B = E1.b;
constexpr K2 F1 = tf2x32(E0.a,E0.b,0u,1u);  // sub2
constexpr unsigned SK2A = F1.a, SK2B = F1.b;

// med buffer: [0]=hstar [1]=base [2]=cnt [3]=lo_cut [4]=rk_cut ; [8..71]=lo, [72..135]=rk
#define MED_CAP 64

// LDS row stride for GEMM tiles: 40 shorts (80B) -> bank walk 20*row mod 32 (2-way max)
#define LDW 40

// ---------------- weight transpose helper ----------------
__device__ inline void tconv(const float* __restrict__ src, unsigned short* __restrict__ dst,
                             int R, int C, int r0, int c0){
  __shared__ unsigned short tile[64][72];
  int t = threadIdx.x;
  int tr = t>>2, tc = (t&3)*16;
  #pragma unroll
  for (int u=0;u<16;u++)
    tile[tr][tc+u] = bf16rne(src[(size_t)(r0+tr)*C + c0 + tc + u]);
  __syncthreads();
  unsigned short v[16];
  #pragma unroll
  for (int u=0;u<16;u++) v[u] = tile[tc+u][tr];
  uint4* vv = (uint4*)v;
  uint4* o = (uint4*)&dst[(size_t)(c0+tr)*R + r0 + tc];
  o[0] = vv[0]; o[1] = vv[1];
}

// ---------------- front: edges (0..511) + x tiles (512..767) + weights ----------------
__global__ void front_k(const int* __restrict__ ei,
                        unsigned* __restrict__ keys1, unsigned* __restrict__ keys2,
                        unsigned* __restrict__ hist1, unsigned* __restrict__ hist2,
                        unsigned* __restrict__ indeg, unsigned* __restrict__ outdeg,
                        unsigned* __restrict__ bits,
                        const float* __restrict__ x, unsigned short* __restrict__ x_bf,
                        unsigned short* __restrict__ xT_bf,
                        const float* __restrict__ W0, unsigned short* __restrict__ WT0,
                        const float* __restrict__ W1, unsigned short* __restrict__ WT1,
                        const float* __restrict__ W2, unsigned short* __restrict__ WT2,
                        const float* __restrict__ fcW, unsigned short* __restrict__ fcWT){
  int b = blockIdx.x, t = threadIdx.x;
  if (b < 512){
    unsigned e = b*256u + t;
    K2 r1 = tf2x32(SK1A, SK1B, 0u, e);
    unsigned k1 = r1.a ^ r1.b;
    K2 r2 = tf2x32(SK2A, SK2B, 0u, e);
    unsigned k2 = r2.a ^ r2.b;
    keys1[e] = k1; keys2[e] = k2;
    atomicAdd(&hist1[k1>>16], 1u);
    atomicAdd(&hist2[k2>>16], 1u);
    unsigned s = (unsigned)ei[e], d = (unsigned)ei[NE+e];
    atomicAdd(&outdeg[s], 1u);
    atomicAdd(&indeg[d], 1u);
    atomicOr(&bits[d*128 + (s>>5)], 1u << (s&31));
    if (e < NN) atomicOr(&bits[e*128 + (e>>5)], 1u << (e&31));
    return;
  }
  int b2 = b - 512;
  if (b2 < 256){                                        // x tile: emit x_bf + xT_bf
    __shared__ unsigned short tile[64][72];
    int r0 = (b2>>2)*64, c0 = (b2&3)*64;
    int tr = t>>2, tc = (t&3)*16;
    #pragma unroll
    for (int u=0;u<16;u++)
      tile[tr][tc+u] = bf16rne(x[(size_t)(r0+tr)*DIN + c0 + tc + u]);
    __syncthreads();
    unsigned short vr[16];
    #pragma unroll
    for (int u=0;u<16;u++) vr[u] = tile[tr][tc+u];
    uint4* rv = (uint4*)vr;
    uint4* xo = (uint4*)&x_bf[(size_t)(r0+tr)*DIN + c0 + tc];
    xo[0] = rv[0]; xo[1] = rv[1];
    unsigned short v[16];
    #pragma unroll
    for (int u=0;u<16;u++) v[u] = tile[tc+u][tr];
    uint4* vv = (uint4*)v;
    uint4* o = (uint4*)&xT_bf[(size_t)(c0+tr)*NN + r0 + tc];
    o[0] = vv[0]; o[1] = vv[1];
  } else if (b2 < 352){                                 // 3 enc weights: 32 tiles each
    int idx = b2 - 256;
    int z = idx >> 5, tl = idx & 31;
    const float* src = z==0?W0 : z==1?W1 : W2;
    unsigned short* dst = z==0?WT0 : z==1?WT1 : WT2;
    tconv(src, dst, DIN, DHID, (tl>>3)*64, (tl&7)*64);
  } else {                                              // fcW: 24 tiles
    int by = b2 - 352;
    tconv(fcW, fcWT, DCAT, DOUT, by*64, 0);
  }
}

// ---------------- single-launch quad scan (wave-parallel decoupled lookback) + med1 ----------------
__global__ void scanAll_k(const unsigned* __restrict__ in0, const unsigned* __restrict__ in1,
                          const unsigned* __restrict__ in2, const unsigned* __restrict__ in3,
                          unsigned* __restrict__ o0, unsigned* __restrict__ o1,
                          unsigned* __restrict__ o2, unsigned* __restrict__ o3,
                          unsigned* __restrict__ c0, unsigned* __restrict__ c1,
                          unsigned* __restrict__ c2, unsigned* __restrict__ c3,
                          unsigned* __restrict__ flags, const unsigned* __restrict__ hist2,
                          unsigned* __restrict__ med){
  int y = blockIdx.y;
  int nblk = (y<2) ? (NBINS/256) : (NN/256);
  int xb = blockIdx.x;
  if (xb >= nblk) return;
  const unsigned* in = y==0?in0 : y==1?in1 : y==2?in2 : in3;
  unsigned* o        = y==0?o0  : y==1?o1  : y==2?o2  : o3;
  unsigned* c        = y==0?c0  : y==1?c1  : y==2?c2  : c3;
  __shared__ unsigned s[256];
  __shared__ unsigned base_s;
  int t = threadIdx.x; unsigned i = xb*256u + t;
  unsigned v = in[i]; s[t] = v; __syncthreads();
  for (int off=1; off<256; off<<=1){
    unsigned u = (t>=off)?s[t-off]:0u; __syncthreads();
    s[t]+=u; __syncthreads();
  }
  unsigned excl = s[t]-v;
  unsigned total = s[255];
  unsigned* f = flags + y*256;
  if (xb == 0){
    if (t==0){ atomicExch(&f[0], 0x80000000u | total); base_s = 0u; }
  } else {
    if (t==0) atomicExch(&f[xb], 0x40000000u | total);
    if (t < 64){
      unsigned base = 0; int start = xb-1; int done = 0;
      while (!done && start >= 0){
        int idx = start - t;
        unsigned fv = 0;
        if (idx >= 0){
          do { fv = atomicAdd(&f[idx], 0u); } while (!(fv & 0xC0000000u));
        }
        unsigned long long pm = __ballot(idx >= 0 && (fv & 0x80000000u));
        unsigned contrib;
        if (pm){
          int plane = __ffsll((long long)pm) - 1;
          contrib = (idx >= 0 && t <= plane) ? (fv & 0x3FFFFFFFu) : 0u;
          done = 1;
        } else {
          contrib = (idx >= 0) ? (fv & 0x3FFFFFFFu) : 0u;
          start -= 64;
        }
        for (int oo=32; oo>0; oo>>=1) contrib += __shfl_xor(contrib, oo, 64);
        base += contrib;
      }
      if (t==0){ atomicExch(&f[xb], 0x80000000u | (base + total)); base_s = base; }
    }
  }
  __syncthreads();
  unsigned res = excl + base_s;
  o[i] = res; c[i] = res;
  if (y==1){
    unsigned hv = hist2[i];
    if (res <= HALF_E && HALF_E < res + hv){ med[0] = i; med[1] = res; }
  }
}

// ---------------- scat1 (packed u64 payload) + median-bin collection ----------------
__global__ void scat1med_k(const unsigned* __restrict__ keys1, const unsigned* __restrict__ keys2,
                           unsigned* __restrict__ cursor, unsigned long long* __restrict__ slowstb,
                           unsigned* __restrict__ med){
  int e = blockIdx.x*256 + threadIdx.x;
  unsigned k = keys1[e];
  unsigned p = atomicAdd(&cursor[k>>16], 1u);
  slowstb[p] = ((unsigned long long)(k & 0xFFFFu) << 32) | (unsigned)e;
  unsigned k2 = keys2[e];
  if ((k2>>16) == med[0]){
    unsigned idx = atomicAdd(&med[2], 1u);
    if (idx < MED_CAP){ med[8+idx] = k2 & 0xFFFFu; med[72+idx] = (unsigned)e; }
  }
}

// ---------------- rank1 + CSR scatter (blocks 0..EB-1) + med3 cut-selection (block EB) ----------------
__global__ void rankscat_k(const int* __restrict__ ei, const unsigned* __restrict__ keys1,
                           const unsigned* __restrict__ prefix, const unsigned* __restrict__ hist,
                           const unsigned long long* __restrict__ slowstb,
                           unsigned* __restrict__ curin, unsigned* __restrict__ curout,
                           unsigned* __restrict__ in_list, unsigned* __restrict__ out_list,
                           unsigned* __restrict__ med){
  int b = blockIdx.x, t = threadIdx.x;
  if (b == NE/256){
    unsigned n = med[2]; if (n > MED_CAP) n = MED_CAP;
    unsigned qcut = HALF_E - med[1];
    if (t < (int)n){
      unsigned lo = med[8+t], rk = med[72+t], pos = 0;
      for (unsigned j=0;j<n;j++){
        unsigned lj = med[8+j], rj = med[72+j];
        if (lj < lo || (lj==lo && rj < rk)) pos++;
      }
      if (pos == qcut){ med[3] = lo; med[4] = rk; }
    }
    return;
  }
  int e = b*256 + t;
  unsigned k = keys1[e], h = k>>16;
  unsigned long long me = ((unsigned long long)(k & 0xFFFFu) << 32) | (unsigned)e;
  unsigned base = prefix[h], n = hist[h], r = 0;
  for (unsigned j=0;j<n;j++)
    r += (slowstb[base+j] < me) ? 1u : 0u;
  unsigned rk = base + r;
  unsigned s = (unsigned)ei[e], d = (unsigned)ei[NE+e];
  unsigned p = atomicAdd(&curin[d], 1u);  in_list[p] = s;
  unsigned q = atomicAdd(&curout[s], 1u); out_list[q] = d | (rk<<12);
}

// ---------------- reach (blocks 0..NN-1) + cut (NN..2NN-1): 4-group vectorized gathers ----------------
__global__ void reachcut_k(const unsigned* __restrict__ bits, const unsigned* __restrict__ in_off,
                           const unsigned* __restrict__ in_list, const unsigned* __restrict__ indeg,
                           unsigned* __restrict__ reach, float* __restrict__ cntinv,
                           const float* __restrict__ x, const unsigned* __restrict__ out_off,
                           const unsigned* __restrict__ outdeg, const unsigned* __restrict__ out_list,
                           const unsigned* __restrict__ keys2, const unsigned* __restrict__ med,
                           unsigned short* __restrict__ cut_bf){
  __shared__ unsigned nbr[256];
  int b = blockIdx.x, t = threadIdx.x;
  int g = t>>6, l = t&63;
  if (b < NN){
    __shared__ unsigned combA[4][64], combB[4][64];
    int i = b;
    unsigned off = in_off[i], deg = indeg[i];
    unsigned a0=0u, a1=0u;
    if (g==0){ uint2 sb = *(const uint2*)&bits[(size_t)i*128 + l*2]; a0=sb.x; a1=sb.y; }
    for (unsigned base=0; base<deg; base+=256){
      unsigned ch = min(deg-base, 256u);
      if (t < (int)ch) nbr[t] = in_list[off+base+t];
      __syncthreads();
      for (unsigned j=g; j<ch; j+=4){
        uint2 v = *(const uint2*)&bits[(size_t)nbr[j]*128 + l*2];
        a0 |= v.x; a1 |= v.y;
      }
      __syncthreads();
    }
    combA[g][l]=a0; combB[g][l]=a1;
    __syncthreads();
    if (g==0){
      a0 |= combA[1][l] | combA[2][l] | combA[3][l];
      a1 |= combB[1][l] | combB[2][l] | combB[3][l];
      uint2 o; o.x=a0; o.y=a1;
      *(uint2*)&reach[(size_t)i*128 + l*2] = o;
      int c = __popc(a0) + __popc(a1);
      for (int oo=32;oo>0;oo>>=1) c += __shfl_xor(c, oo, 64);
      if (l==0) cntinv[i] = 1.0f / (float)c;
    }
  } else {
    __shared__ unsigned key_s[256];
    __shared__ float4 combF[4][64];
    __shared__ int combC[4];
    int s = b - NN;
    unsigned off = out_off[s], deg = outdeg[s];
    unsigned hs = med[0], loc = med[3], rkc = med[4];
    float4 acc = {0.f,0.f,0.f,0.f}; int cnt = 0;
    for (unsigned base=0; base<deg; base+=256){
      unsigned ch = min(deg-base, 256u);
      if (t < (int)ch){
        unsigned v = out_list[off+base+t];
        nbr[t] = v;
        key_s[t] = keys2[v >> 12];
      }
      __syncthreads();
      for (unsigned j=g; j<ch; j+=4){
        unsigned v = nbr[j], k2 = key_s[j];
        unsigned rk = v >> 12;
        unsigned h = k2>>16, lo = k2 & 0xFFFFu;
        unsigned keep = (h > hs) || (h == hs && (lo > loc || (lo == loc && rk >= rkc)));
        if (keep){
          cnt++;
          float4 xv = *(const float4*)&x[(size_t)(v & 0xFFFu)*DIN + l*4];
          acc.x += xv.x; acc.y += xv.y; acc.z += xv.z; acc.w += xv.w;
        }
      }
      __syncthreads();
    }
    combF[g][l] = acc;
    if (l==0) combC[g] = cnt;
    __syncthreads();
    if (g==0){
      float4 a1 = combF[1][l], a2 = combF[2][l], a3 = combF[3][l];
      float sx = acc.x+a1.x+a2.x+a3.x, sy = acc.y+a1.y+a2.y+a3.y;
      float sz = acc.z+a1.z+a2.z+a3.z, sw = acc.w+a1.w+a2.w+a3.w;
      int c = combC[0]+combC[1]+combC[2]+combC[3];
      float vx, vy, vz, vw;
      if (c){ float ci = 1.0f/(float)c; vx=sx*ci; vy=sy*ci; vz=sz*ci; vw=sw*ci; }
      else { float4 xv = *(const float4*)&x[(size_t)s*DIN + l*4]; vx=xv.x; vy=xv.y; vz=xv.z; vw=xv.w; }
      uint2 o;
      o.x = (unsigned)bf16rne(vx) | ((unsigned)bf16rne(vy)<<16);
      o.y = (unsigned)bf16rne(vz) | ((unsigned)bf16rne(vw)<<16);
      *(uint2*)&cut_bf[(size_t)s*DIN + l*4] = o;
    }
  }
}

// ---------------- ego bit-GEMM, BN=64, split-K=4, K_STEP=128, stride-40 LDS (r14 proven) ----------------
__global__ void bitgemm_k(const unsigned* __restrict__ reach, const unsigned short* __restrict__ xT,
                          float* __restrict__ pbuf){
  __shared__ __align__(16) unsigned short bt[4][64*LDW];
  int t = threadIdx.x, w = t>>6, l = t&63;
  int m0 = blockIdx.x*64, n0 = blockIdx.y*64;
  int kbase = blockIdx.z*(NN/4);
  int srow = t>>2, sg = t&3;
  int arow = m0 + 16*w + (l&15);
  int lg = l>>4;
  f32x4 acc[4];
  #pragma unroll
  for (int c=0;c<4;c++) acc[c] = f32x4{0.f,0.f,0.f,0.f};

  for (int it=0; it<8; ++it){
    int kk = kbase + it*128;
    __syncthreads();
    #pragma unroll
    for (int s=0;s<4;s++){
      uint4 v = *(const uint4*)&xT[(size_t)(n0+srow)*NN + kk + 32*s + sg*8];
      *(uint4*)&bt[s][srow*LDW + sg*8] = v;
    }
    __syncthreads();
    unsigned rw[4];
    *(uint4*)rw = *(const uint4*)&reach[(size_t)arow*128 + (kk>>5)];
    #pragma unroll
    for (int s=0;s<4;s++){
      unsigned byte = (rw[s] >> (8*lg)) & 0xFFu;
      union { short8 s8; unsigned u[4]; } af;
      #pragma unroll
      for (int pp=0;pp<4;pp++){
        unsigned b0 = (byte>>(2*pp))&1u, b1 = (byte>>(2*pp+1))&1u;
        af.u[pp] = b0*0x3F80u | b1*0x3F800000u;
      }
      #pragma unroll
      for (int c=0;c<4;c++){
        int brow = 16*c + (l&15);
        short8 bf = *(const short8*)&bt[s][brow*LDW + lg*8];
        acc[c] = __builtin_amdgcn_mfma_f32_16x16x32_bf16(af.s8, bf, acc[c], 0,0,0);
      }
    }
  }
  size_t zoff = (size_t)blockIdx.z*NN*DIN;
  #pragma unroll
  for (int c=0;c<4;c++){
    #pragma unroll
    for (int r=0;r<4;r++){
      int row = m0 + 16*w + 4*lg + r;
      int col = n0 + 16*c + (l&15);
      pbuf[zoff + (size_t)row*DIN + col] = acc[c][r];
    }
  }
}

// ---------------- reduce partials + scale -> ego_bf ----------------
__global__ void redscale_k(const float* __restrict__ pbuf, const float* __restrict__ cntinv,
                           unsigned short* __restrict__ ego_bf){
  int g = blockIdx.x*256 + threadIdx.x;
  const size_t S = (size_t)NN*DIN/4;
  const float4* p4 = (const float4*)pbuf;
  float4 a = p4[g], b = p4[g+S], c = p4[g+2*S], d = p4[g+3*S];
  int row = (g*4)>>8;
  float ci = cntinv[row];
  float vx = (a.x+b.x+c.x+d.x)*ci, vy = (a.y+b.y+c.y+d.y)*ci;
  float vz = (a.z+b.z+c.z+d.z)*ci, vw = (a.w+b.w+c.w+d.w)*ci;
  uint2 o;
  o.x = (unsigned)bf16rne(vx) | ((unsigned)bf16rne(vy)<<16);
  o.y = (unsigned)bf16rne(vz) | ((unsigned)bf16rne(vw)<<16);
  ((uint2*)ego_bf)[g] = o;
}

// ---------------- aggregate features over in-edges: 4-group vectorized ----------------
__global__ void aggfeat_k(const unsigned short* __restrict__ ego_bf, const unsigned short* __restrict__ cut_bf,
                          const unsigned* __restrict__ in_off, const unsigned* __restrict__ indeg,
                          const unsigned* __restrict__ in_list,
                          unsigned short* __restrict__ aggE, unsigned short* __restrict__ aggC){
  __shared__ unsigned nbr[256];
  __shared__ float4 combE[4][64], combD[4][64];
  int i = blockIdx.x, t = threadIdx.x;
  int g = t>>6, l = t&63;
  unsigned off = in_off[i], deg = indeg[i];
  float4 ae = {0.f,0.f,0.f,0.f}, ac = {0.f,0.f,0.f,0.f};
  for (unsigned base=0; base<deg; base+=256){
    unsigned ch = min(deg-base, 256u);
    if (t < (int)ch) nbr[t] = in_list[off+base+t];
    __syncthreads();
    for (unsigned j=g; j<ch; j+=4){
      unsigned s = nbr[j];
      uint2 ev = *(const uint2*)&ego_bf[(size_t)s*DIN + l*4];
      uint2 cv = *(const uint2*)&cut_bf[(size_t)s*DIN + l*4];
      ae.x += bf2f((unsigned short)(ev.x & 0xFFFFu));
      ae.y += bf2f((unsigned short)(ev.x >> 16));
      ae.z += bf2f((unsigned short)(ev.y & 0xFFFFu));
      ae.w += bf2f((unsigned short)(ev.y >> 16));
      ac.x += bf2f((unsigned short)(cv.x & 0xFFFFu));
      ac.y += bf2f((unsigned short)(cv.x >> 16));
      ac.z += bf2f((unsigned short)(cv.y & 0xFFFFu));
      ac.w += bf2f((unsigned short)(cv.y >> 16));
    }
    __syncthreads();
  }
  combE[g][l] = ae; combD[g][l] = ac;
  __syncthreads();
  if (g==0){
    float4 e1 = combE[1][l], e2 = combE[2][l], e3 = combE[3][l];
    float4 c1 = combD[1][l], c2 = combD[2][l], c3 = combD[3][l];
    float ex = ae.x+e1.x+e2.x+e3.x, ey = ae.y+e1.y+e2.y+e3.y;
    float ez = ae.z+e1.z+e2.z+e3.z, ew = ae.w+e1.w+e2.w+e3.w;
    float cx = ac.x+c1.x+c2.x+c3.x, cy = ac.y+c1.y+c2.y+c3.y;
    float cz = ac.z+c1.z+c2.z+c3.z, cw = ac.w+c1.w+c2.w+c3.w;
    uint2 oe, oc;
    oe.x = (unsigned)bf16rne(ex) | ((unsigned)bf16rne(ey)<<16);
    oe.y = (unsigned)bf16rne(ez) | ((unsigned)bf16rne(ew)<<16);
    oc.x = (unsigned)bf16rne(cx) | ((unsigned)bf16rne(cy)<<16);
    oc.y = (unsigned)bf16rne(cz) | ((unsigned)bf16rne(cw)<<16);
    *(uint2*)&aggE[(size_t)i*DIN + l*4] = oe;
    *(uint2*)&aggC[(size_t)i*DIN + l*4] = oc;
  }
}

// ---------------- merged encoder GEMM (z: 0=ego-agg,1=cut-agg,2=glob), stride-40 LDS ----------------
__global__ void gemm3_k(const unsigned short* __restrict__ aggE, const unsigned short* __restrict__ aggC,
                        const unsigned short* __restrict__ xbf,
                        const unsigned short* __restrict__ WTe, const unsigned short* __restrict__ WTc,
                        const unsigned short* __restrict__ WTg,
                        const float* __restrict__ eb, const float* __restrict__ cb, const float* __restrict__ gb,
                        const unsigned* __restrict__ indeg, unsigned short* __restrict__ hcat){
  __shared__ __align__(16) unsigned short at[4][64*LDW];
  __shared__ __align__(16) unsigned short bt[4][64*LDW];
  int z = blockIdx.z;
  const unsigned short* A  = z==0? aggE : z==1? aggC : xbf;
  const unsigned short* BT = z==0? WTe  : z==1? WTc  : WTg;
  const float* bias        = z==0? eb   : z==1? cb   : gb;
  int t = threadIdx.x, w = t>>6, l = t&63;
  int n0 = blockIdx.x*64, m0 = blockIdx.y*64;
  int srow = t>>2, sg = t&3;
  int lg = l>>4;
  f32x4 acc[4];
  #pragma unroll
  for (int c=0;c<4;c++) acc[c] = f32x4{0.f,0.f,0.f,0.f};

  for (int it=0; it<2; ++it){
    int kk = it*128;
    __syncthreads();
    #pragma unroll
    for (int s=0;s<4;s++){
      uint4 va = *(const uint4*)&A [(size_t)(m0+srow)*DIN + kk + 32*s + sg*8];
      uint4 vb = *(const uint4*)&BT[(size_t)(n0+srow)*DIN + kk + 32*s + sg*8];
      *(uint4*)&at[s][srow*LDW + sg*8] = va;
      *(uint4*)&bt[s][srow*LDW + sg*8] = vb;
    }
    __syncthreads();
    int ar = 16*w + (l&15);
    #pragma unroll
    for (int s=0;s<4;s++){
      short8 af = *(const short8*)&at[s][ar*LDW + lg*8];
      #pragma unroll
      for (int c=0;c<4;c++){
        int brow = 16*c + (l&15);
        short8 bf = *(const short8*)&bt[s][brow*LDW + lg*8];
        acc[c] = __builtin_amdgcn_mfma_f32_16x16x32_bf16(af, bf, acc[c], 0,0,0);
      }
    }
  }
  #pragma unroll
  for (int c=0;c<4;c++){
    #pragma unroll
    for (int r=0;r<4;r++){
      int row = m0 + 16*w + 4*lg + r;
      int col = n0 + 16*c + (l&15);
      float scale = (z<2) ? (float)indeg[row] : 1.0f;
      float v = acc[c][r] + bias[col]*scale;
      if (z<2) v = fmaxf(v, 0.f);
      hcat[(size_t)row*DCAT + z*DHID + col] = bf16rne(v);
    }
  }
}

// ---------------- fc GEMM split-K=4, stride-40 LDS ----------------
__global__ void fcgemm_k(const unsigned short* __restrict__ hcat, const unsigned short* __restrict__ fcWT,
                         float* __restrict__ fcpart){
  __shared__ __align__(16) unsigned short at[4][64*LDW];
  __shared__ __align__(16) unsigned short bt[4][64*LDW];
  int t = threadIdx.x, w = t>>6, l = t&63;
  int m0 = blockIdx.x*64;
  int kbase = blockIdx.y*(DCAT/4);
  int srow = t>>2, sg = t&3;
  int lg = l>>4;
  f32x4 acc[4];
  #pragma unroll
  for (int c=0;c<4;c++) acc[c] = f32x4{0.f,0.f,0.f,0.f};

  for (int it=0; it<3; ++it){
    int kk = kbase + it*128;
    __syncthreads();
    #pragma unroll
    for (int s=0;s<4;s++){
      uint4 va = *(const uint4*)&hcat [(size_t)(m0+srow)*DCAT + kk + 32*s + sg*8];
      uint4 vb = *(const uint4*)&fcWT[(size_t)srow*DCAT + kk + 32*s + sg*8];
      *(uint4*)&at[s][srow*LDW + sg*8] = va;
      *(uint4*)&bt[s][srow*LDW + sg*8] = vb;
    }
    __syncthreads();
    int ar = 16*w + (l&15);
    #pragma unroll
    for (int s=0;s<4;s++){
      short8 af = *(const short8*)&at[s][ar*LDW + lg*8];
      #pragma unroll
      for (int c=0;c<4;c++){
        int brow = 16*c + (l&15);
        short8 bf = *(const short8*)&bt[s][brow*LDW + lg*8];
        acc[c] = __builtin_amdgcn_mfma_f32_16x16x32_bf16(af, bf, acc[c], 0,0,0);
      }
    }
  }
  size_t zoff = (size_t)blockIdx.y*NN*DOUT;
  #pragma unroll
  for (int c=0;c<4;c++){
    #pragma unroll
    for (int r=0;r<4;r++){
      int row = m0 + 16*w + 4*lg + r;
      int col = 16*c + (l&15);
      fcpart[zoff + (size_t)row*DOUT + col] = acc[c][r];
    }
  }
}

// ---------------- finish: sum partials + bias + log_softmax ----------------
__global__ void fcfin_k(const float* __restrict__ fcpart, const float* __restrict__ fcb,
                        float* __restrict__ out){
  int i = blockIdx.x, l = threadIdx.x;
  const size_t S = (size_t)NN*DOUT;
  size_t idx = (size_t)i*DOUT + l;
  float v = fcpart[idx] + fcpart[idx+S] + fcpart[idx+2*S] + fcpart[idx+3*S] + fcb[l];
  float m = v;
  for (int o=32;o>0;o>>=1) m = fmaxf(m, __shfl_xor(m, o, 64));
  float e = __expf(v - m), s = e;
  for (int o=32;o>0;o>>=1) s += __shfl_xor(s, o, 64);
  out[idx] = (v - m) - logf(s);
}

// ---------------- host launch ----------------
static inline size_t alignup(size_t x){ return (x + 255) & ~(size_t)255; }

extern "C" void kernel_launch(void* const* d_in, const int* in_sizes, int n_in,
                              void* d_out, int out_size, void* d_ws, size_t ws_size,
                              hipStream_t stream) {
  const float* x      = (const float*)d_in[0];
  const int*   ei     = (const int*)  d_in[1];
  const float* ego_W  = (const float*)d_in[2];
  const float* ego_b  = (const float*)d_in[3];
  const float* cut_W  = (const float*)d_in[4];
  const float* cut_b  = (const float*)d_in[5];
  const float* glob_W = (const float*)d_in[6];
  const float* glob_b = (const float*)d_in[7];
  const float* fc_W   = (const float*)d_in[8];
  const float* fc_b   = (const float*)d_in[9];
  float* out = (float*)d_out;

  char* base = (char*)d_ws;
  char* p = base;
  #define ALLOC(ty, name, cnt) ty* name = (ty*)p; p += alignup(sizeof(ty)*(size_t)(cnt));
  ALLOC(char,           R0,      (size_t)4*NN*DIN*4);   // 16MB: sort temps -> pbuf -> hcat
  // ---- zero region (one memset) ----
  ALLOC(unsigned,       bits,    NN*128);
  ALLOC(unsigned,       indeg,   NN);
  ALLOC(unsigned,       outdeg,  NN);
  ALLOC(unsigned,       hist1,   NBINS);
  ALLOC(unsigned,       hist2,   NBINS);
  ALLOC(unsigned,       med,     256);
  ALLOC(unsigned,       flags,   1024);
  char* zero_end = p;
  // ---- rest ----
  ALLOC(unsigned,       in_off,  NN);
  ALLOC(unsigned,       out_off, NN);
  ALLOC(unsigned,       curin,   NN);
  ALLOC(unsigned,       curout,  NN);
  ALLOC(unsigned,       in_list, NE);
  ALLOC(unsigned,       out_list,NE);
  ALLOC(unsigned,       reach,   NN*128);
  ALLOC(float,          cntinv,  NN);
  ALLOC(unsigned short, x_bf,    (size_t)NN*DIN);
  ALLOC(unsigned short, xT_bf,   (size_t)DIN*NN);
  ALLOC(unsigned short, ego_bf,  (size_t)NN*DIN);
  ALLOC(unsigned short, cut_bf,  (size_t)NN*DIN);
  ALLOC(unsigned short, aggE_bf, (size_t)NN*DIN);
  ALLOC(unsigned short, aggC_bf, (size_t)NN*DIN);
  ALLOC(unsigned short, egoWT,   (size_t)DHID*DIN);
  ALLOC(unsigned short, cutWT,   (size_t)DHID*DIN);
  ALLOC(unsigned short, globWT,  (size_t)DHID*DIN);
  ALLOC(unsigned short, fcWT,    (size_t)DOUT*DCAT);
  ALLOC(unsigned,       prefix1, NBINS);
  ALLOC(unsigned,       cursor1, NBINS);
  ALLOC(unsigned,       prefix2, NBINS);
  ALLOC(unsigned,       cursor2, NBINS);
  ALLOC(float,          fcpart,  (size_t)4*NN*DOUT);
  #undef ALLOC
  size_t need = (size_t)(p - base);
  if (ws_size < need){
    hipMemsetAsync(d_out, 0x7F, (size_t)out_size*sizeof(float), stream);
    return;
  }
  float*          pbuf = (float*)R0;
  unsigned short* hcat = (unsigned short*)R0;
  char* q = R0;
  #define OALLOC(ty, name, cnt) ty* name = (ty*)q; q += alignup(sizeof(ty)*(size_t)(cnt));
  OALLOC(unsigned,            keys1,   NE);
  OALLOC(unsigned,            keys2,   NE);
  OALLOC(unsigned long long,  slowstb, NE);
  #undef OALLOC

  const int EB = NE/256;

  // 1) zero [bits|indeg|outdeg|hist1|hist2|med|flags]
  hipMemsetAsync(bits, 0, (size_t)(zero_end - (char*)bits), stream);
  // 2) keys + hists + degrees + bits + ALL conversions
  hipLaunchKernelGGL(front_k, dim3(888), dim3(256), 0, stream,
                     ei, keys1, keys2, hist1, hist2, indeg, outdeg, bits,
                     x, x_bf, xT_bf, ego_W, egoWT, cut_W, cutWT, glob_W, globWT, fc_W, fcWT);
  // 3) quad scan (wave-parallel lookback) + median-bin locate
  hipLaunchKernelGGL(scanAll_k, dim3(NBINS/256, 4), dim3(256), 0, stream,
                     hist1, hist2, indeg, outdeg,
                     prefix1, prefix2, in_off, out_off,
                     cursor1, cursor2, curin, curout, flags, hist2, med);
  // 4) round-1 binned scatter (packed payload) + median-bin member collection
  hipLaunchKernelGGL(scat1med_k, dim3(EB), dim3(256), 0, stream,
                     keys1, keys2, cursor1, slowstb, med);
  // 5) round-1 rank + CSR scatter (rk packed in out_list) + cut-element selection
  hipLaunchKernelGGL(rankscat_k, dim3(EB+1), dim3(256), 0, stream,
                     ei, keys1, prefix1, hist1, slowstb, curin, curout, in_list, out_list, med);
  // 6) 2-hop reach + cut feature (4-group vectorized, inline keep)
  hipLaunchKernelGGL(reachcut_k, dim3(2*NN), dim3(256), 0, stream,
                     bits, in_off, in_list, indeg, reach, cntinv,
                     x, out_off, outdeg, out_list, keys2, med, cut_bf);
  // 7) ego bit-GEMM, BN=64 (pbuf overlays sort temps; keys dead after step 6)
  hipLaunchKernelGGL(bitgemm_k, dim3(NN/64, DIN/64, 4), dim3(256), 0, stream, reach, xT_bf, pbuf);
  // 8) reduce partials + scale
  hipLaunchKernelGGL(redscale_k, dim3((NN*DIN/4)/256), dim3(256), 0, stream, pbuf, cntinv, ego_bf);
  // 9) feature aggregation (4-group vectorized)
  hipLaunchKernelGGL(aggfeat_k, dim3(NN), dim3(256), 0, stream,
                     ego_bf, cut_bf, in_off, indeg, in_list, aggE_bf, aggC_bf);
  // 10) encoders -> hcat (overlays pbuf, dead after 8)
  hipLaunchKernelGGL(gemm3_k, dim3(DHID/64, NN/64, 3), dim3(256), 0, stream,
                     aggE_bf, aggC_bf, x_bf, egoWT, cutWT, globWT,
                     ego_b, cut_b, glob_b, indeg, hcat);
  // 11) fc split-K=4
  hipLaunchKernelGGL(fcgemm_k, dim3(NN/64, 4), dim3(256), 0, stream, hcat, fcWT, fcpart);
  // 12) sum partials + bias + log_softmax
  hipLaunchKernelGGL(fcfin_k, dim3(NN), dim3(64), 0, stream, fcpart, fc_b, out);
}